// Round 5
// baseline (5167.727 us; speedup 1.0000x reference)
//
#include <hip/hip_runtime.h>
#include <stdint.h>

#define L_SEQ 2048
#define DIM 1536
#define NH 24
#define HD 64
#define NQKV 4608

typedef unsigned short u16;
typedef __attribute__((ext_vector_type(4))) float f32x4;
typedef __attribute__((ext_vector_type(8))) short bf16x8;
typedef __attribute__((ext_vector_type(4))) u16 u16x4;
typedef __attribute__((ext_vector_type(8))) u16 u16x8;

__device__ __forceinline__ u16 f2bf(float f) {
  unsigned u = __builtin_bit_cast(unsigned, f);
  u += 0x7fffu + ((u >> 16) & 1u);
  return (u16)(u >> 16);
}
__device__ __forceinline__ float b2f(u16 u) {
  return __builtin_bit_cast(float, (unsigned)u << 16);
}

__device__ __forceinline__ void gload_lds16(const void* g, void* lds) {
  __builtin_amdgcn_global_load_lds(
      (const __attribute__((address_space(1))) unsigned int*)g,
      (__attribute__((address_space(3))) unsigned int*)lds, 16, 0, 0);
}

// ---------------- cast f32 -> bf16 ----------------
__global__ __launch_bounds__(256) void cast_kernel(const float* __restrict__ in,
                                                   u16* __restrict__ out, int n4) {
  int i = blockIdx.x * 256 + threadIdx.x;
  if (i >= n4) return;
  f32x4 v = ((const f32x4*)in)[i];
  u16x4 o;
  o.x = f2bf(v.x);
  o.y = f2bf(v.y);
  o.z = f2bf(v.z);
  o.w = f2bf(v.w);
  ((u16x4*)out)[i] = o;
}

// ---------------- GEMM: C[M][N] = A[M][K] * B[N][K]^T + bias ----------------
// m97-style: 128x128 tile, BK=32, 4 waves (2x2), 16x16x32 MFMA, global_load_lds.
// WRITE_BF16=1 -> u16 bf16 out; WRITE_BF16=0 -> float out (d_out is float!).
template <int WRITE_BF16>
__global__ __launch_bounds__(256) void gemm_bt(const u16* __restrict__ A,
                                               const u16* __restrict__ B,
                                               const float* __restrict__ bias,
                                               void* __restrict__ Cout,
                                               int M, int N, int K) {
  __shared__ u16 As[128 * 32];
  __shared__ u16 Bs[128 * 32];
  const int nb = N >> 7;
  const int bx = (int)blockIdx.x % nb;
  const int by = (int)blockIdx.x / nb;
  const int tid = threadIdx.x;
  const int lane = tid & 63;
  const int wv = tid >> 6;
  const int wr = wv >> 1, wc = wv & 1;

  f32x4 acc[4][4];
#pragma unroll
  for (int i = 0; i < 4; i++)
#pragma unroll
    for (int j = 0; j < 4; j++) acc[i][j] = (f32x4)(0.0f);

  const int e0 = tid * 8;
  const int r0 = e0 >> 5, c0 = e0 & 31;
  const u16* Ag0 = A + (size_t)(by * 128 + r0) * K + c0;
  const u16* Ag1 = A + (size_t)(by * 128 + r0 + 64) * K + c0;
  const u16* Bg0 = B + (size_t)(bx * 128 + r0) * K + c0;
  const u16* Bg1 = B + (size_t)(bx * 128 + r0 + 64) * K + c0;
  char* AsB = (char*)As + wv * 1024;  // wave-uniform LDS base (+ lane*16 by HW)
  char* BsB = (char*)Bs + wv * 1024;
  const int kc = (lane >> 4) * 8;

  for (int k0 = 0; k0 < K; k0 += 32) {
    __syncthreads();
    gload_lds16(Ag0 + k0, AsB);
    gload_lds16(Ag1 + k0, AsB + 4096);
    gload_lds16(Bg0 + k0, BsB);
    gload_lds16(Bg1 + k0, BsB + 4096);
    __syncthreads();

    bf16x8 af[4], bfr[4];
#pragma unroll
    for (int mt = 0; mt < 4; mt++)
      af[mt] = *(const bf16x8*)&As[(wr * 64 + mt * 16 + (lane & 15)) * 32 + kc];
#pragma unroll
    for (int nt = 0; nt < 4; nt++)
      bfr[nt] = *(const bf16x8*)&Bs[(wc * 64 + nt * 16 + (lane & 15)) * 32 + kc];
#pragma unroll
    for (int mt = 0; mt < 4; mt++)
#pragma unroll
      for (int nt = 0; nt < 4; nt++)
        acc[mt][nt] = __builtin_amdgcn_mfma_f32_16x16x32_bf16(af[mt], bfr[nt],
                                                              acc[mt][nt], 0, 0, 0);
  }

  // C/D layout: col = lane&15, row = (lane>>4)*4 + reg  [m89/m91 verified]
  const int colb = bx * 128 + wc * 64 + (lane & 15);
  const int rowb = by * 128 + wr * 64 + ((lane >> 4) << 2);
#pragma unroll
  for (int nt = 0; nt < 4; nt++) {
    const int col = colb + nt * 16;
    const float bv = bias[col];
#pragma unroll
    for (int mt = 0; mt < 4; mt++) {
#pragma unroll
      for (int r = 0; r < 4; r++) {
        const int row = rowb + mt * 16 + r;
        float v = acc[mt][nt][r] + bv;
        if (WRITE_BF16)
          ((u16*)Cout)[(size_t)row * N + col] = f2bf(v);
        else
          ((float*)Cout)[(size_t)row * N + col] = v;
      }
    }
  }
}

// ---------------- QK-RMSNorm, in place on bf16 qkv [L][3*DIM] ----------------
__global__ __launch_bounds__(256) void qknorm_bf16(u16* __restrict__ qkv,
                                                   const float* __restrict__ gq,
                                                   const float* __restrict__ gk) {
  const int h = blockIdx.y;
  const int l = blockIdx.x * 4 + (threadIdx.x >> 6);
  const int lane = threadIdx.x & 63;
  u16* qp = qkv + (size_t)l * NQKV + h * HD;
  const float q = b2f(qp[lane]);
  const float k = b2f(qp[DIM + lane]);
  float sq = q * q, sk = k * k;
#pragma unroll
  for (int m = 32; m; m >>= 1) {
    sq += __shfl_xor(sq, m);
    sk += __shfl_xor(sk, m);
  }
  const float rq = rsqrtf(sq * (1.0f / 64.0f) + 1e-6f);
  const float rk = rsqrtf(sk * (1.0f / 64.0f) + 1e-6f);
  qp[lane] = f2bf(q * rq * gq[lane] * 0.125f);  // fold 1/sqrt(HD)
  qp[DIM + lane] = f2bf(k * rk * gk[lane]);
}

// ---------------- VALU flash: 4 q-rows per block, full softmax in LDS ----------
__global__ __launch_bounds__(256) void flash_valu(const u16* __restrict__ qkv,
                                                  u16* __restrict__ Ob) {
  const int h = blockIdx.y;
  const int q0 = blockIdx.x * 4;
  const int t = threadIdx.x;
  __shared__ float qs[4][64];
  __shared__ float p[4][L_SEQ];
  __shared__ float red[256];

  qs[t >> 6][t & 63] = b2f(qkv[(size_t)(q0 + (t >> 6)) * NQKV + h * HD + (t & 63)]);
  __syncthreads();

  float lm[4] = {-1e30f, -1e30f, -1e30f, -1e30f};
  for (int kv = t; kv < L_SEQ; kv += 256) {
    const u16* kr = qkv + (size_t)kv * NQKV + DIM + h * HD;
    float s[4] = {0.f, 0.f, 0.f, 0.f};
#pragma unroll
    for (int c = 0; c < HD; c += 8) {
      u16x8 kk = *(const u16x8*)(kr + c);
#pragma unroll
      for (int j = 0; j < 8; j++) {
        const float kf = b2f(kk[j]);
#pragma unroll
        for (int r = 0; r < 4; r++) s[r] = fmaf(qs[r][c + j], kf, s[r]);
      }
    }
#pragma unroll
    for (int r = 0; r < 4; r++) {
      p[r][kv] = s[r];
      lm[r] = fmaxf(lm[r], s[r]);
    }
  }

  float M4[4], S4[4];
#pragma unroll 1
  for (int r = 0; r < 4; r++) {
    __syncthreads();
    red[t] = lm[r];
    __syncthreads();
    for (int off = 128; off > 0; off >>= 1) {
      if (t < off) red[t] = fmaxf(red[t], red[t + off]);
      __syncthreads();
    }
    M4[r] = red[0];
  }
  __syncthreads();

  float ls[4] = {0.f, 0.f, 0.f, 0.f};
  for (int kv = t; kv < L_SEQ; kv += 256) {
#pragma unroll
    for (int r = 0; r < 4; r++) {
      const float e = __expf(p[r][kv] - M4[r]);
      p[r][kv] = e;
      ls[r] += e;
    }
  }
#pragma unroll 1
  for (int r = 0; r < 4; r++) {
    __syncthreads();
    red[t] = ls[r];
    __syncthreads();
    for (int off = 128; off > 0; off >>= 1) {
      if (t < off) red[t] += red[t + off];
      __syncthreads();
    }
    S4[r] = red[0];
  }
  __syncthreads();

  const int d = t & 63, g = t >> 6;
  float o[4] = {0.f, 0.f, 0.f, 0.f};
  const u16* vbase = qkv + 2 * DIM + h * HD + d;
  for (int kv = g; kv < L_SEQ; kv += 4) {
    const float vf = b2f(vbase[(size_t)kv * NQKV]);
#pragma unroll
    for (int r = 0; r < 4; r++) o[r] = fmaf(p[r][kv], vf, o[r]);
  }
#pragma unroll 1
  for (int r = 0; r < 4; r++) {
    __syncthreads();
    red[t] = o[r];
    __syncthreads();
    if (t < 64) {
      const float ot = (red[t] + red[t + 64] + red[t + 128] + red[t + 192]) / S4[r];
      Ob[(size_t)(q0 + r) * DIM + h * HD + t] = f2bf(ot);
    }
  }
}

// ---------------- launcher ----------------
extern "C" void kernel_launch(void* const* d_in, const int* in_sizes, int n_in,
                              void* d_out, int out_size, void* d_ws, size_t ws_size,
                              hipStream_t stream) {
  const float* x = (const float*)d_in[0];
  const float* w_qkv = (const float*)d_in[1];
  const float* b_qkv = (const float*)d_in[2];
  const float* w_proj = (const float*)d_in[3];
  const float* b_proj = (const float*)d_in[4];
  const float* g_q = (const float*)d_in[5];
  const float* g_k = (const float*)d_in[6];

  char* ws = (char*)d_ws;
  u16* x_b = (u16*)(ws + 0);           // 2048*1536*2 = 6291456
  u16* wqkv_b = (u16*)(ws + 6291456);  // 4608*1536*2 = 14155776
  u16* wpj_b = (u16*)(ws + 20447232);  // 1536*1536*2 = 4718592
  u16* qkv = (u16*)(ws + 25165824);    // 2048*4608*2 = 18874368
  u16* Ob = (u16*)(ws + 44040192);     // 2048*1536*2 = 6291456 -> total 50331648

  cast_kernel<<<(L_SEQ * DIM / 4 + 255) / 256, 256, 0, stream>>>(x, x_b, L_SEQ * DIM / 4);
  cast_kernel<<<(NQKV * DIM / 4 + 255) / 256, 256, 0, stream>>>(w_qkv, wqkv_b, NQKV * DIM / 4);
  cast_kernel<<<(DIM * DIM / 4 + 255) / 256, 256, 0, stream>>>(w_proj, wpj_b, DIM * DIM / 4);

  // qkv = x @ w_qkv^T + b_qkv  (bf16 out, in-place qknorm next)
  gemm_bt<1><<<(L_SEQ / 128) * (NQKV / 128), 256, 0, stream>>>(
      x_b, wqkv_b, b_qkv, (void*)qkv, L_SEQ, NQKV, DIM);

  qknorm_bf16<<<dim3(L_SEQ / 4, NH), 256, 0, stream>>>(qkv, g_q, g_k);

  flash_valu<<<dim3(L_SEQ / 4, NH), 256, 0, stream>>>(qkv, Ob);

  // d_out is FLOAT (reference output dtype is float32): write f32.
  gemm_bt<0><<<(L_SEQ / 128) * (DIM / 128), 256, 0, stream>>>(
      Ob, wpj_b, b_proj, d_out, L_SEQ, DIM, DIM);
}

// Round 6
// 257.759 us; speedup vs baseline: 20.0487x; 20.0487x over previous
//
#include <hip/hip_runtime.h>
#include <stdint.h>

#define L_SEQ 2048
#define DIM 1536
#define NH 24
#define HD 64
#define NQKV 4608

typedef unsigned short u16;
typedef __attribute__((ext_vector_type(4))) float f32x4;
typedef __attribute__((ext_vector_type(8))) short bf16x8;
typedef __attribute__((ext_vector_type(4))) u16 u16x4;
typedef __attribute__((ext_vector_type(8))) u16 u16x8;

__device__ __forceinline__ u16 f2bf(float f) {
  unsigned u = __builtin_bit_cast(unsigned, f);
  u += 0x7fffu + ((u >> 16) & 1u);
  return (u16)(u >> 16);
}
__device__ __forceinline__ float b2f(u16 u) {
  return __builtin_bit_cast(float, (unsigned)u << 16);
}

__device__ __forceinline__ void gload_lds16(const void* g, void* lds) {
  __builtin_amdgcn_global_load_lds(
      (const __attribute__((address_space(1))) unsigned int*)g,
      (__attribute__((address_space(3))) unsigned int*)lds, 16, 0, 0);
}

// ---------------- cast f32 -> bf16 ----------------
__global__ __launch_bounds__(256) void cast_kernel(const float* __restrict__ in,
                                                   u16* __restrict__ out, int n4) {
  int i = blockIdx.x * 256 + threadIdx.x;
  if (i >= n4) return;
  f32x4 v = ((const f32x4*)in)[i];
  u16x4 o;
  o.x = f2bf(v.x);
  o.y = f2bf(v.y);
  o.z = f2bf(v.z);
  o.w = f2bf(v.w);
  ((u16x4*)out)[i] = o;
}

// ---------------- GEMM: C[M][N] = A[M][K] * B[N][K]^T + bias ----------------
// m97-style: 128x128 tile, BK=32, 4 waves (2x2), 16x16x32 MFMA, global_load_lds.
template <int WRITE_BF16>
__global__ __launch_bounds__(256) void gemm_bt(const u16* __restrict__ A,
                                               const u16* __restrict__ B,
                                               const float* __restrict__ bias,
                                               void* __restrict__ Cout,
                                               int M, int N, int K) {
  __shared__ u16 As[128 * 32];
  __shared__ u16 Bs[128 * 32];
  const int nb = N >> 7;
  const int bx = (int)blockIdx.x % nb;
  const int by = (int)blockIdx.x / nb;
  const int tid = threadIdx.x;
  const int lane = tid & 63;
  const int wv = tid >> 6;
  const int wr = wv >> 1, wc = wv & 1;

  f32x4 acc[4][4];
#pragma unroll
  for (int i = 0; i < 4; i++)
#pragma unroll
    for (int j = 0; j < 4; j++) acc[i][j] = (f32x4)(0.0f);

  const int e0 = tid * 8;
  const int r0 = e0 >> 5, c0 = e0 & 31;
  const u16* Ag0 = A + (size_t)(by * 128 + r0) * K + c0;
  const u16* Ag1 = A + (size_t)(by * 128 + r0 + 64) * K + c0;
  const u16* Bg0 = B + (size_t)(bx * 128 + r0) * K + c0;
  const u16* Bg1 = B + (size_t)(bx * 128 + r0 + 64) * K + c0;
  char* AsB = (char*)As + wv * 1024;  // wave-uniform LDS base (+ lane*16 by HW)
  char* BsB = (char*)Bs + wv * 1024;
  const int kc = (lane >> 4) * 8;

  for (int k0 = 0; k0 < K; k0 += 32) {
    __syncthreads();
    gload_lds16(Ag0 + k0, AsB);
    gload_lds16(Ag1 + k0, AsB + 4096);
    gload_lds16(Bg0 + k0, BsB);
    gload_lds16(Bg1 + k0, BsB + 4096);
    __syncthreads();

    bf16x8 af[4], bfr[4];
#pragma unroll
    for (int mt = 0; mt < 4; mt++)
      af[mt] = *(const bf16x8*)&As[(wr * 64 + mt * 16 + (lane & 15)) * 32 + kc];
#pragma unroll
    for (int nt = 0; nt < 4; nt++)
      bfr[nt] = *(const bf16x8*)&Bs[(wc * 64 + nt * 16 + (lane & 15)) * 32 + kc];
#pragma unroll
    for (int mt = 0; mt < 4; mt++)
#pragma unroll
      for (int nt = 0; nt < 4; nt++)
        acc[mt][nt] = __builtin_amdgcn_mfma_f32_16x16x32_bf16(af[mt], bfr[nt],
                                                              acc[mt][nt], 0, 0, 0);
  }

  // C/D layout: col = lane&15, row = (lane>>4)*4 + reg
  const int colb = bx * 128 + wc * 64 + (lane & 15);
  const int rowb = by * 128 + wr * 64 + ((lane >> 4) << 2);
#pragma unroll
  for (int nt = 0; nt < 4; nt++) {
    const int col = colb + nt * 16;
    const float bv = bias[col];
#pragma unroll
    for (int mt = 0; mt < 4; mt++) {
#pragma unroll
      for (int r = 0; r < 4; r++) {
        const int row = rowb + mt * 16 + r;
        float v = acc[mt][nt][r] + bv;
        if (WRITE_BF16)
          ((u16*)Cout)[(size_t)row * N + col] = f2bf(v);
        else
          ((float*)Cout)[(size_t)row * N + col] = v;
      }
    }
  }
}

// ---------------- QK-RMSNorm + layout rearrange (bf16 qkv input) ------------
// qkv bf16 [L][3*DIM] -> Qh/Kh bf16 [H][L][64] (q scaled by 1/8), Vt bf16 [H][64][L]
__global__ __launch_bounds__(256) void qkvnorm_kernel(const u16* __restrict__ qkv,
                                                      const float* __restrict__ gq,
                                                      const float* __restrict__ gk,
                                                      u16* __restrict__ Qh,
                                                      u16* __restrict__ Kh,
                                                      u16* __restrict__ Vt) {
  const int h = blockIdx.y;
  const int lblk = blockIdx.x * 64;
  const int tid = threadIdx.x;
  const int lane = tid & 63, wv = tid >> 6;
  __shared__ u16 vt[64][64];
  const float gqv = gq[lane] * 0.125f;  // fold 1/sqrt(HD)
  const float gkv = gk[lane];
#pragma unroll 1
  for (int i = 0; i < 16; i++) {
    const int l = lblk + wv * 16 + i;
    const size_t base = (size_t)l * NQKV + h * HD + lane;
    const float q = b2f(qkv[base]);
    const float k = b2f(qkv[base + DIM]);
    float sq = q * q, sk = k * k;
#pragma unroll
    for (int m = 32; m; m >>= 1) {
      sq += __shfl_xor(sq, m);
      sk += __shfl_xor(sk, m);
    }
    const float rq = rsqrtf(sq * (1.0f / 64.0f) + 1e-6f);
    const float rk = rsqrtf(sk * (1.0f / 64.0f) + 1e-6f);
    const size_t ho = ((size_t)h * L_SEQ + l) * HD + lane;
    Qh[ho] = f2bf(q * rq * gqv);
    Kh[ho] = f2bf(k * rk * gkv);
    vt[wv * 16 + i][lane] = qkv[base + 2 * DIM];  // v: passthrough bf16
  }
  __syncthreads();
  // transposed V write: thread t -> d = t>>2, 16 l-columns starting (t&3)*16
  const int d = tid >> 2;
  const int cb = (tid & 3) * 16;
  u16* dst = Vt + ((size_t)h * HD + d) * L_SEQ + lblk + cb;
#pragma unroll
  for (int j0 = 0; j0 < 4; j0++) {
    u16x4 o;
    o.x = vt[cb + j0 * 4 + 0][d];
    o.y = vt[cb + j0 * 4 + 1][d];
    o.z = vt[cb + j0 * 4 + 2][d];
    o.w = vt[cb + j0 * 4 + 3][d];
    *(u16x4*)(dst + j0 * 4) = o;
  }
}

// ---------------- MFMA flash attention (cross-validated vs VALU flash) -------
// grid (L/64, H), 4 waves x 16 q-rows, KV tile = 32.
__global__ __launch_bounds__(256) void flash_kernel(const u16* __restrict__ Qh,
                                                    const u16* __restrict__ Kh,
                                                    const u16* __restrict__ Vt,
                                                    u16* __restrict__ O) {
  const int h = blockIdx.y;
  const int qblk = blockIdx.x * 64;
  const int tid = threadIdx.x;
  const int lane = tid & 63, wv = tid >> 6;
  __shared__ u16 Ks[32][72];     // [kv][d], +8 pad
  __shared__ u16 Vs[64][40];     // [d][kv], +8 pad
  __shared__ u16 Ps[4][16][40];  // per-wave P, +8 pad

  const int kc = (lane >> 4) * 8;
  const int qrow = qblk + wv * 16 + (lane & 15);
  const u16* Qp = Qh + ((size_t)h * L_SEQ + qrow) * HD;
  bf16x8 qf0 = *(const bf16x8*)(Qp + kc);  // A-frag: row=lane&15, k=(lane>>4)*8+j
  bf16x8 qf1 = *(const bf16x8*)(Qp + 32 + kc);

  f32x4 oacc[4];
#pragma unroll
  for (int dt = 0; dt < 4; dt++) oacc[dt] = (f32x4)(0.0f);
  float mr[4] = {-1e30f, -1e30f, -1e30f, -1e30f};
  float lr[4] = {0.0f, 0.0f, 0.0f, 0.0f};

  const u16* Kg = Kh + ((size_t)h * L_SEQ + (tid >> 3)) * HD + (tid & 7) * 8;
  const u16* Vg = Vt + ((size_t)h * HD + (tid >> 2)) * L_SEQ + (tid & 3) * 8;
  u16* KsW = &Ks[tid >> 3][(tid & 7) * 8];
  u16* VsW = &Vs[tid >> 2][(tid & 3) * 8];

  for (int kb = 0; kb < L_SEQ; kb += 32) {
    __syncthreads();  // previous PV reads of Vs done
    *(bf16x8*)KsW = *(const bf16x8*)(Kg + (size_t)kb * HD);
    *(bf16x8*)VsW = *(const bf16x8*)(Vg + kb);
    __syncthreads();

    f32x4 s0 = (f32x4)(0.0f), s1 = (f32x4)(0.0f);
    {
      bf16x8 k00 = *(const bf16x8*)&Ks[lane & 15][kc];
      bf16x8 k01 = *(const bf16x8*)&Ks[lane & 15][32 + kc];
      bf16x8 k10 = *(const bf16x8*)&Ks[16 + (lane & 15)][kc];
      bf16x8 k11 = *(const bf16x8*)&Ks[16 + (lane & 15)][32 + kc];
      s0 = __builtin_amdgcn_mfma_f32_16x16x32_bf16(qf0, k00, s0, 0, 0, 0);
      s0 = __builtin_amdgcn_mfma_f32_16x16x32_bf16(qf1, k01, s0, 0, 0, 0);
      s1 = __builtin_amdgcn_mfma_f32_16x16x32_bf16(qf0, k10, s1, 0, 0, 0);
      s1 = __builtin_amdgcn_mfma_f32_16x16x32_bf16(qf1, k11, s1, 0, 0, 0);
    }

    float scl[4];
#pragma unroll
    for (int r = 0; r < 4; r++) {
      float mx = fmaxf(s0[r], s1[r]);
      mx = fmaxf(mx, __shfl_xor(mx, 1));
      mx = fmaxf(mx, __shfl_xor(mx, 2));
      mx = fmaxf(mx, __shfl_xor(mx, 4));
      mx = fmaxf(mx, __shfl_xor(mx, 8));
      const float nm = fmaxf(mr[r], mx);
      scl[r] = __expf(mr[r] - nm);
      mr[r] = nm;
      const float p0 = __expf(s0[r] - nm);
      const float p1 = __expf(s1[r] - nm);
      float sum = p0 + p1;
      sum += __shfl_xor(sum, 1);
      sum += __shfl_xor(sum, 2);
      sum += __shfl_xor(sum, 4);
      sum += __shfl_xor(sum, 8);
      lr[r] = lr[r] * scl[r] + sum;
      Ps[wv][(lane >> 4) * 4 + r][lane & 15] = f2bf(p0);
      Ps[wv][(lane >> 4) * 4 + r][16 + (lane & 15)] = f2bf(p1);
    }
#pragma unroll
    for (int dt = 0; dt < 4; dt++) {
#pragma unroll
      for (int r = 0; r < 4; r++) oacc[dt][r] *= scl[r];
    }
    __syncthreads();  // P visible (Vs still valid)

    bf16x8 pf = *(const bf16x8*)&Ps[wv][lane & 15][kc];
#pragma unroll
    for (int dt = 0; dt < 4; dt++) {
      bf16x8 vf = *(const bf16x8*)&Vs[dt * 16 + (lane & 15)][kc];
      oacc[dt] = __builtin_amdgcn_mfma_f32_16x16x32_bf16(pf, vf, oacc[dt], 0, 0, 0);
    }
  }

#pragma unroll
  for (int dt = 0; dt < 4; dt++) {
    const int col = h * HD + dt * 16 + (lane & 15);
#pragma unroll
    for (int r = 0; r < 4; r++) {
      const int row = qblk + wv * 16 + (lane >> 4) * 4 + r;
      O[(size_t)row * DIM + col] = f2bf(oacc[dt][r] / lr[r]);
    }
  }
}

// ---------------- launcher ----------------
extern "C" void kernel_launch(void* const* d_in, const int* in_sizes, int n_in,
                              void* d_out, int out_size, void* d_ws, size_t ws_size,
                              hipStream_t stream) {
  const float* x = (const float*)d_in[0];
  const float* w_qkv = (const float*)d_in[1];
  const float* b_qkv = (const float*)d_in[2];
  const float* w_proj = (const float*)d_in[3];
  const float* b_proj = (const float*)d_in[4];
  const float* g_q = (const float*)d_in[5];
  const float* g_k = (const float*)d_in[6];

  char* ws = (char*)d_ws;
  u16* x_b = (u16*)(ws + 0);           // 6291456
  u16* wqkv_b = (u16*)(ws + 6291456);  // 14155776
  u16* wpj_b = (u16*)(ws + 20447232);  // 4718592
  u16* qkv = (u16*)(ws + 25165824);    // 18874368
  u16* Qh = (u16*)(ws + 44040192);     // 6291456
  u16* Kh = (u16*)(ws + 50331648);     // 6291456
  u16* Vt = (u16*)(ws + 56623104);     // 6291456
  u16* Ob = (u16*)(ws + 62914560);     // 6291456 -> total 69206016

  cast_kernel<<<(L_SEQ * DIM / 4 + 255) / 256, 256, 0, stream>>>(x, x_b, L_SEQ * DIM / 4);
  cast_kernel<<<(NQKV * DIM / 4 + 255) / 256, 256, 0, stream>>>(w_qkv, wqkv_b, NQKV * DIM / 4);
  cast_kernel<<<(DIM * DIM / 4 + 255) / 256, 256, 0, stream>>>(w_proj, wpj_b, DIM * DIM / 4);

  gemm_bt<1><<<(L_SEQ / 128) * (NQKV / 128), 256, 0, stream>>>(
      x_b, wqkv_b, b_qkv, (void*)qkv, L_SEQ, NQKV, DIM);

  qkvnorm_kernel<<<dim3(L_SEQ / 64, NH), 256, 0, stream>>>(qkv, g_q, g_k, Qh, Kh, Vt);

  flash_kernel<<<dim3(L_SEQ / 64, NH), 256, 0, stream>>>(Qh, Kh, Vt, Ob);

  // d_out is float32
  gemm_bt<0><<<(L_SEQ / 128) * (DIM / 128), 256, 0, stream>>>(
      Ob, wpj_b, b_proj, d_out, L_SEQ, DIM, DIM);
}

// Round 7
// 206.861 us; speedup vs baseline: 24.9817x; 1.2460x over previous
//
#include <hip/hip_runtime.h>
#include <stdint.h>

#define L_SEQ 2048
#define DIM 1536
#define NH 24
#define HD 64
#define NQKV 4608

typedef unsigned short u16;
typedef __attribute__((ext_vector_type(4))) float f32x4;
typedef __attribute__((ext_vector_type(8))) short bf16x8;
typedef __attribute__((ext_vector_type(4))) u16 u16x4;
typedef __attribute__((ext_vector_type(8))) u16 u16x8;

__device__ __forceinline__ u16 f2bf(float f) {
  unsigned u = __builtin_bit_cast(unsigned, f);
  u += 0x7fffu + ((u >> 16) & 1u);
  return (u16)(u >> 16);
}
__device__ __forceinline__ float b2f(u16 u) {
  return __builtin_bit_cast(float, (unsigned)u << 16);
}

__device__ __forceinline__ void gload_lds16(const void* g, void* lds) {
  __builtin_amdgcn_global_load_lds(
      (const __attribute__((address_space(1))) unsigned int*)g,
      (__attribute__((address_space(3))) unsigned int*)lds, 16, 0, 0);
}

// ---------------- cast f32 -> bf16 ----------------
__global__ __launch_bounds__(256) void cast_kernel(const float* __restrict__ in,
                                                   u16* __restrict__ out, int n4) {
  int i = blockIdx.x * 256 + threadIdx.x;
  if (i >= n4) return;
  f32x4 v = ((const f32x4*)in)[i];
  u16x4 o;
  o.x = f2bf(v.x);
  o.y = f2bf(v.y);
  o.z = f2bf(v.z);
  o.w = f2bf(v.w);
  ((u16x4*)out)[i] = o;
}

// ---------------- GEMM: C[M][N] = A[M][K] * B[N][K]^T + bias ----------------
// m97-style: 128x128 tile, BK=32, 4 waves (2x2), 16x16x32 MFMA, global_load_lds.
template <int WRITE_BF16>
__global__ __launch_bounds__(256) void gemm_bt(const u16* __restrict__ A,
                                               const u16* __restrict__ B,
                                               const float* __restrict__ bias,
                                               void* __restrict__ Cout,
                                               int M, int N, int K) {
  __shared__ u16 As[128 * 32];
  __shared__ u16 Bs[128 * 32];
  const int nb = N >> 7;
  const int bx = (int)blockIdx.x % nb;
  const int by = (int)blockIdx.x / nb;
  const int tid = threadIdx.x;
  const int lane = tid & 63;
  const int wv = tid >> 6;
  const int wr = wv >> 1, wc = wv & 1;

  f32x4 acc[4][4];
#pragma unroll
  for (int i = 0; i < 4; i++)
#pragma unroll
    for (int j = 0; j < 4; j++) acc[i][j] = (f32x4)(0.0f);

  const int e0 = tid * 8;
  const int r0 = e0 >> 5, c0 = e0 & 31;
  const u16* Ag0 = A + (size_t)(by * 128 + r0) * K + c0;
  const u16* Ag1 = A + (size_t)(by * 128 + r0 + 64) * K + c0;
  const u16* Bg0 = B + (size_t)(bx * 128 + r0) * K + c0;
  const u16* Bg1 = B + (size_t)(bx * 128 + r0 + 64) * K + c0;
  char* AsB = (char*)As + wv * 1024;  // wave-uniform LDS base (+ lane*16 by HW)
  char* BsB = (char*)Bs + wv * 1024;
  const int kc = (lane >> 4) * 8;

  for (int k0 = 0; k0 < K; k0 += 32) {
    __syncthreads();
    gload_lds16(Ag0 + k0, AsB);
    gload_lds16(Ag1 + k0, AsB + 4096);
    gload_lds16(Bg0 + k0, BsB);
    gload_lds16(Bg1 + k0, BsB + 4096);
    __syncthreads();

    bf16x8 af[4], bfr[4];
#pragma unroll
    for (int mt = 0; mt < 4; mt++)
      af[mt] = *(const bf16x8*)&As[(wr * 64 + mt * 16 + (lane & 15)) * 32 + kc];
#pragma unroll
    for (int nt = 0; nt < 4; nt++)
      bfr[nt] = *(const bf16x8*)&Bs[(wc * 64 + nt * 16 + (lane & 15)) * 32 + kc];
#pragma unroll
    for (int mt = 0; mt < 4; mt++)
#pragma unroll
      for (int nt = 0; nt < 4; nt++)
        acc[mt][nt] = __builtin_amdgcn_mfma_f32_16x16x32_bf16(af[mt], bfr[nt],
                                                              acc[mt][nt], 0, 0, 0);
  }

  // C/D layout: col = lane&15, row = (lane>>4)*4 + reg
  const int colb = bx * 128 + wc * 64 + (lane & 15);
  const int rowb = by * 128 + wr * 64 + ((lane >> 4) << 2);
#pragma unroll
  for (int nt = 0; nt < 4; nt++) {
    const int col = colb + nt * 16;
    const float bv = bias[col];
#pragma unroll
    for (int mt = 0; mt < 4; mt++) {
#pragma unroll
      for (int r = 0; r < 4; r++) {
        const int row = rowb + mt * 16 + r;
        float v = acc[mt][nt][r] + bv;
        if (WRITE_BF16)
          ((u16*)Cout)[(size_t)row * N + col] = f2bf(v);
        else
          ((float*)Cout)[(size_t)row * N + col] = v;
      }
    }
  }
}

// ---------------- QK-RMSNorm + layout rearrange (bf16 qkv input) ------------
// qkv bf16 [L][3*DIM] -> Qh/Kh bf16 [H][L][64] (q scaled by 1/8), Vt bf16 [H][64][L]
__global__ __launch_bounds__(256) void qkvnorm_kernel(const u16* __restrict__ qkv,
                                                      const float* __restrict__ gq,
                                                      const float* __restrict__ gk,
                                                      u16* __restrict__ Qh,
                                                      u16* __restrict__ Kh,
                                                      u16* __restrict__ Vt) {
  const int h = blockIdx.y;
  const int lblk = blockIdx.x * 64;
  const int tid = threadIdx.x;
  const int lane = tid & 63, wv = tid >> 6;
  __shared__ u16 vt[64][64];
  const float gqv = gq[lane] * 0.125f;  // fold 1/sqrt(HD)
  const float gkv = gk[lane];
#pragma unroll 1
  for (int i = 0; i < 16; i++) {
    const int l = lblk + wv * 16 + i;
    const size_t base = (size_t)l * NQKV + h * HD + lane;
    const float q = b2f(qkv[base]);
    const float k = b2f(qkv[base + DIM]);
    float sq = q * q, sk = k * k;
#pragma unroll
    for (int m = 32; m; m >>= 1) {
      sq += __shfl_xor(sq, m);
      sk += __shfl_xor(sk, m);
    }
    const float rq = rsqrtf(sq * (1.0f / 64.0f) + 1e-6f);
    const float rk = rsqrtf(sk * (1.0f / 64.0f) + 1e-6f);
    const size_t ho = ((size_t)h * L_SEQ + l) * HD + lane;
    Qh[ho] = f2bf(q * rq * gqv);
    Kh[ho] = f2bf(k * rk * gkv);
    vt[wv * 16 + i][lane] = qkv[base + 2 * DIM];  // v: passthrough bf16
  }
  __syncthreads();
  const int d = tid >> 2;
  const int cb = (tid & 3) * 16;
  u16* dst = Vt + ((size_t)h * HD + d) * L_SEQ + lblk + cb;
#pragma unroll
  for (int j0 = 0; j0 < 4; j0++) {
    u16x4 o;
    o.x = vt[cb + j0 * 4 + 0][d];
    o.y = vt[cb + j0 * 4 + 1][d];
    o.z = vt[cb + j0 * 4 + 2][d];
    o.w = vt[cb + j0 * 4 + 3][d];
    *(u16x4*)(dst + j0 * 4) = o;
  }
}

// ---------------- MFMA flash attention, KVBLK=64, XOR-swizzled LDS ----------
// grid (L/64, H), 4 waves x 16 q-rows. T14: next-tile K/V prefetched to regs.
// LDS rows are 128B; col16 ^= (row&7)<<3 on both write and read (T2/G4).
__global__ __launch_bounds__(256) void flash_kernel(const u16* __restrict__ Qh,
                                                    const u16* __restrict__ Kh,
                                                    const u16* __restrict__ Vt,
                                                    u16* __restrict__ O) {
  const int h = blockIdx.y;
  const int qblk = blockIdx.x * 64;
  const int tid = threadIdx.x;
  const int lane = tid & 63, wv = tid >> 6;
  __shared__ u16 Ks[64][64];      // [kv][d]
  __shared__ u16 Vs[64][64];      // [d][kv]
  __shared__ u16 Ps[4][16][64];   // per-wave [q][kv]

  const int l4 = lane & 15;
  const int kc = (lane >> 4) * 8;
  const int swz = (lane & 7) << 3;  // read-side swizzle: rows ≡ l4 (mod 8)

  const int qrow = qblk + wv * 16 + l4;
  const u16* Qp = Qh + ((size_t)h * L_SEQ + qrow) * HD;
  const bf16x8 qf0 = *(const bf16x8*)(Qp + kc);  // A-frag: row=l4, k=kc+j
  const bf16x8 qf1 = *(const bf16x8*)(Qp + 32 + kc);

  f32x4 oacc[4];
#pragma unroll
  for (int dt = 0; dt < 4; dt++) oacc[dt] = (f32x4)(0.0f);
  float mr[4] = {-1e30f, -1e30f, -1e30f, -1e30f};
  float lr[4] = {0.f, 0.f, 0.f, 0.f};

  // staging geometry
  const int krow = tid >> 3;            // 0..31
  const int kcol = (tid & 7) * 8;       // 0..56
  const u16* Kg = Kh + (size_t)h * L_SEQ * HD + (size_t)krow * HD + kcol;
  u16* KsW0 = &Ks[krow][kcol ^ ((krow & 7) << 3)];
  u16* KsW1 = KsW0 + 32 * 64;           // (krow+32)&7 == krow&7
  const int vd = tid >> 2;              // 0..63
  const int vcol = (tid & 3) * 16;      // 0,16,32,48
  const u16* Vg = Vt + ((size_t)h * HD + vd) * L_SEQ;
  u16* VsW0 = &Vs[vd][vcol ^ ((vd & 7) << 3)];
  u16* VsW1 = &Vs[vd][(vcol + 8) ^ ((vd & 7) << 3)];

  // prologue: tile 0 into regs
  bf16x8 kr0 = *(const bf16x8*)(Kg);
  bf16x8 kr1 = *(const bf16x8*)(Kg + 32 * HD);
  bf16x8 vr0 = *(const bf16x8*)(Vg + vcol);
  bf16x8 vr1 = *(const bf16x8*)(Vg + vcol + 8);

  for (int kb = 0; kb < L_SEQ; kb += 64) {
    __syncthreads();  // all waves done reading previous tile's Ks/Vs
    *(bf16x8*)KsW0 = kr0;
    *(bf16x8*)KsW1 = kr1;
    *(bf16x8*)VsW0 = vr0;
    *(bf16x8*)VsW1 = vr1;
    if (kb + 64 < L_SEQ) {  // T14: issue next-tile loads, consumed after next barrier
      kr0 = *(const bf16x8*)(Kg + (size_t)(kb + 64) * HD);
      kr1 = *(const bf16x8*)(Kg + (size_t)(kb + 96) * HD);
      vr0 = *(const bf16x8*)(Vg + kb + 64 + vcol);
      vr1 = *(const bf16x8*)(Vg + kb + 72 + vcol);
    }
    __syncthreads();  // staging visible

    // QK^T: 4 kv-subtiles of 16
    f32x4 s[4];
#pragma unroll
    for (int st = 0; st < 4; st++) {
      const u16* kp = &Ks[st * 16 + l4][0];
      bf16x8 ka = *(const bf16x8*)(kp + (kc ^ swz));
      bf16x8 kb2 = *(const bf16x8*)(kp + ((kc + 32) ^ swz));
      s[st] = __builtin_amdgcn_mfma_f32_16x16x32_bf16(qf0, ka, (f32x4)(0.0f), 0, 0, 0);
      s[st] = __builtin_amdgcn_mfma_f32_16x16x32_bf16(qf1, kb2, s[st], 0, 0, 0);
    }

    // online softmax: C/D row=(lane>>4)*4+r (q), col=l4 (kv within subtile)
    float scl[4];
#pragma unroll
    for (int r = 0; r < 4; r++) {
      float mx = fmaxf(fmaxf(s[0][r], s[1][r]), fmaxf(s[2][r], s[3][r]));
      mx = fmaxf(mx, __shfl_xor(mx, 1));
      mx = fmaxf(mx, __shfl_xor(mx, 2));
      mx = fmaxf(mx, __shfl_xor(mx, 4));
      mx = fmaxf(mx, __shfl_xor(mx, 8));
      const float nm = fmaxf(mr[r], mx);
      scl[r] = __expf(mr[r] - nm);
      mr[r] = nm;
      const float p0 = __expf(s[0][r] - nm);
      const float p1 = __expf(s[1][r] - nm);
      const float p2 = __expf(s[2][r] - nm);
      const float p3 = __expf(s[3][r] - nm);
      float sum = (p0 + p1) + (p2 + p3);
      sum += __shfl_xor(sum, 1);
      sum += __shfl_xor(sum, 2);
      sum += __shfl_xor(sum, 4);
      sum += __shfl_xor(sum, 8);
      lr[r] = lr[r] * scl[r] + sum;
      const int qr = (lane >> 4) * 4 + r;
      const int wsw = (qr & 7) << 3;
      u16* pr = &Ps[wv][qr][0];
      pr[l4 ^ wsw] = f2bf(p0);
      pr[(16 + l4) ^ wsw] = f2bf(p1);
      pr[(32 + l4) ^ wsw] = f2bf(p2);
      pr[(48 + l4) ^ wsw] = f2bf(p3);
    }
#pragma unroll
    for (int dt = 0; dt < 4; dt++)
#pragma unroll
      for (int r = 0; r < 4; r++) oacc[dt][r] *= scl[r];

    // Ps is wave-private; DS ops complete in order within a wave -> no barrier.
    const u16* pp = &Ps[wv][l4][0];
    bf16x8 pf0 = *(const bf16x8*)(pp + (kc ^ swz));
    bf16x8 pf1 = *(const bf16x8*)(pp + ((kc + 32) ^ swz));
#pragma unroll
    for (int dt = 0; dt < 4; dt++) {
      const u16* vp = &Vs[dt * 16 + l4][0];
      bf16x8 vf0 = *(const bf16x8*)(vp + (kc ^ swz));
      bf16x8 vf1 = *(const bf16x8*)(vp + ((kc + 32) ^ swz));
      oacc[dt] = __builtin_amdgcn_mfma_f32_16x16x32_bf16(pf0, vf0, oacc[dt], 0, 0, 0);
      oacc[dt] = __builtin_amdgcn_mfma_f32_16x16x32_bf16(pf1, vf1, oacc[dt], 0, 0, 0);
    }
  }

#pragma unroll
  for (int dt = 0; dt < 4; dt++) {
    const int col = h * HD + dt * 16 + l4;
#pragma unroll
    for (int r = 0; r < 4; r++) {
      const int row = qblk + wv * 16 + (lane >> 4) * 4 + r;
      O[(size_t)row * DIM + col] = f2bf(oacc[dt][r] / lr[r]);
    }
  }
}

// ---------------- launcher ----------------
extern "C" void kernel_launch(void* const* d_in, const int* in_sizes, int n_in,
                              void* d_out, int out_size, void* d_ws, size_t ws_size,
                              hipStream_t stream) {
  const float* x = (const float*)d_in[0];
  const float* w_qkv = (const float*)d_in[1];
  const float* b_qkv = (const float*)d_in[2];
  const float* w_proj = (const float*)d_in[3];
  const float* b_proj = (const float*)d_in[4];
  const float* g_q = (const float*)d_in[5];
  const float* g_k = (const float*)d_in[6];

  char* ws = (char*)d_ws;
  u16* x_b = (u16*)(ws + 0);           // 6291456
  u16* wqkv_b = (u16*)(ws + 6291456);  // 14155776
  u16* wpj_b = (u16*)(ws + 20447232);  // 4718592
  u16* qkv = (u16*)(ws + 25165824);    // 18874368
  u16* Qh = (u16*)(ws + 44040192);     // 6291456
  u16* Kh = (u16*)(ws + 50331648);     // 6291456
  u16* Vt = (u16*)(ws + 56623104);     // 6291456
  u16* Ob = (u16*)(ws + 62914560);     // 6291456 -> total 69206016

  cast_kernel<<<(L_SEQ * DIM / 4 + 255) / 256, 256, 0, stream>>>(x, x_b, L_SEQ * DIM / 4);
  cast_kernel<<<(NQKV * DIM / 4 + 255) / 256, 256, 0, stream>>>(w_qkv, wqkv_b, NQKV * DIM / 4);
  cast_kernel<<<(DIM * DIM / 4 + 255) / 256, 256, 0, stream>>>(w_proj, wpj_b, DIM * DIM / 4);

  gemm_bt<1><<<(L_SEQ / 128) * (NQKV / 128), 256, 0, stream>>>(
      x_b, wqkv_b, b_qkv, (void*)qkv, L_SEQ, NQKV, DIM);

  qkvnorm_kernel<<<dim3(L_SEQ / 64, NH), 256, 0, stream>>>(qkv, g_q, g_k, Qh, Kh, Vt);

  flash_kernel<<<dim3(L_SEQ / 64, NH), 256, 0, stream>>>(Qh, Kh, Vt, Ob);

  // d_out is float32
  gemm_bt<0><<<(L_SEQ / 128) * (DIM / 128), 256, 0, stream>>>(
      Ob, wpj_b, b_proj, d_out, L_SEQ, DIM, DIM);
}